// Round 18
// baseline (288.105 us; speedup 1.0000x reference)
//
#include <hip/hip_runtime.h>
#include <hip/hip_bf16.h>

#define BATCH 8
#define SEQ   512
#define DIM   512
#define NL    64

typedef float f32x4 __attribute__((ext_vector_type(4)));
using bf16x8 = __attribute__((ext_vector_type(8))) short;   // 8 bf16 = 4 VGPRs

// f32 -> bf16 RNE pair-pack via compiler-native casts.
static __device__ __forceinline__ unsigned short bf1c(float f) {
    __hip_bfloat16 h = (__hip_bfloat16)f;
    return *reinterpret_cast<unsigned short*>(&h);
}
static __device__ __forceinline__ unsigned bfpair(float a, float b) {
    return (unsigned)bf1c(a) | ((unsigned)bf1c(b) << 16);
}

// PROBE 0: zeros, full 537 MB (2048 x 256 KB spans), zero loads, 8 VGPR.
__global__ __launch_bounds__(256) void alab_probe0(float* __restrict__ out)
{
    f32x4* ob = (f32x4*)out + (size_t)blockIdx.x * 16384;
    const f32x4 v = {0.f, 0.f, 0.f, 0.f};
    #pragma unroll 8
    for (int it = 0; it < 64; ++it)
        ob[it * 256 + threadIdx.x] = v;
}

// PROBE 1: register-VARYING data, same shell/size, zero loads, low VGPR.
// Isolates data-content from preamble-loads as the bcast-vs-fill gap cause.
__global__ __launch_bounds__(256) void alab_probe1(float* __restrict__ out)
{
    f32x4* ob = (f32x4*)out + (size_t)blockIdx.x * 16384;
    const float base = (float)(threadIdx.x * 97) + (float)blockIdx.x * 0.37f;
    f32x4 v = {base, base + 0.5f, base * 1.25f, base - 3.f};
    #pragma unroll 8
    for (int it = 0; it < 64; ++it) {
        ob[it * 256 + threadIdx.x] = v;
        v += 1.0f;                              // distinct data every iter
    }
}

// proj v7 (MFMA, self-contained) — byte-identical to rounds 14-17.
__global__ __launch_bounds__(256) void alab_proj7(
    const float* __restrict__ head, const float* __restrict__ dep,
    const float* __restrict__ W, const float* __restrict__ bias,
    float* __restrict__ hbuf, float* __restrict__ dbuf)
{
    __shared__ __align__(16) unsigned short A_lds[16 * 520];  // 16.25 KB
    const int bid   = blockIdx.x;
    const int hd    = bid & 1;                  // 0 = head->h, 1 = dep->d
    const int itile = (bid >> 1) & 31;
    const int b     = bid >> 6;
    const int i0    = itile * 16;

    const float* src = hd ? dep  : head;
    float*       dst = hd ? dbuf : hbuf;

    const float* arow = src + ((size_t)b * SEQ + i0) * DIM;
    #pragma unroll
    for (int u = threadIdx.x; u < 1024; u += 256) {
        const int row = u >> 6, kc = (u & 63) * 8;
        const float* p = arow + row * DIM + kc;
        const float4 f0 = *(const float4*)p;
        const float4 f1 = *(const float4*)(p + 4);
        uint4 wv = { bfpair(f0.x, f0.y), bfpair(f0.z, f0.w),
                     bfpair(f1.x, f1.y), bfpair(f1.z, f1.w) };
        *(uint4*)&A_lds[row * 520 + kc] = wv;
    }
    __syncthreads();

    const int lane = threadIdx.x & 63;
    const int w    = threadIdx.x >> 6;          // wave -> l quadrant
    const int lr   = lane & 15;                 // A: i-row / B: l-row / C: col
    const int kg   = lane >> 4;                 // k-group (8 bf16 each)

    const unsigned short* Ab = &A_lds[lr * 520 + kg * 8];
    const float* Wb = W + (size_t)(w * 16 + lr) * (2 * DIM) + hd * DIM + kg * 8;

    f32x4 acc0 = {0.f, 0.f, 0.f, 0.f}, acc1 = {0.f, 0.f, 0.f, 0.f};
    #pragma unroll
    for (int s = 0; s < 16; s += 2) {           // 2 accumulators for ILP
        const bf16x8 a0 = *(const bf16x8*)(Ab + (s + 0) * 32);
        const bf16x8 a1 = *(const bf16x8*)(Ab + (s + 1) * 32);
        const float4 w00 = *(const float4*)(Wb + (s + 0) * 32);
        const float4 w01 = *(const float4*)(Wb + (s + 0) * 32 + 4);
        const float4 w10 = *(const float4*)(Wb + (s + 1) * 32);
        const float4 w11 = *(const float4*)(Wb + (s + 1) * 32 + 4);
        union { bf16x8 v; unsigned u[4]; } b0, b1;
        b0.u[0] = bfpair(w00.x, w00.y); b0.u[1] = bfpair(w00.z, w00.w);
        b0.u[2] = bfpair(w01.x, w01.y); b0.u[3] = bfpair(w01.z, w01.w);
        b1.u[0] = bfpair(w10.x, w10.y); b1.u[1] = bfpair(w10.z, w10.w);
        b1.u[2] = bfpair(w11.x, w11.y); b1.u[3] = bfpair(w11.z, w11.w);
        acc0 = __builtin_amdgcn_mfma_f32_16x16x32_bf16(a0, b0.v, acc0, 0, 0, 0);
        acc1 = __builtin_amdgcn_mfma_f32_16x16x32_bf16(a1, b1.v, acc1, 0, 0, 0);
    }
    const f32x4 acc = acc0 + acc1;

    const int l = w * 16 + lr;
    const int i = i0 + kg * 4;
    const float bb = hd ? 0.f : bias[l];        // bias folded into h
    const f32x4 r = acc + bb;
    *(f32x4*)(dst + ((size_t)b * NL + l) * SEQ + i) = r;
}

// bcast v8 — byte-identical to round 17 (best: 108.9 us total).
__global__ __launch_bounds__(256) void alab_bcast8(
    const float* __restrict__ hbuf, const float* __restrict__ dbuf,
    float* __restrict__ out)
{
    const int t  = threadIdx.x;
    const int q  = blockIdx.x & 3;              // quarter-tile (128 rows)
    const int bl = blockIdx.x >> 2;             // b*NL + l
    const int j4 = t & 127;                     // f32x4 column
    const int rh = t >> 7;                      // row parity
    const int r0 = q * 128;

    const f32x4 dreg = ((const f32x4*)dbuf)[(size_t)bl * (SEQ / 4) + j4];

    float hreg[64];
    const float* hb = hbuf + (size_t)bl * SEQ + r0 + rh;
    #pragma unroll
    for (int it = 0; it < 64; ++it) hreg[it] = hb[it * 2];

    f32x4* ob = (f32x4*)out + ((size_t)bl * SEQ + r0) * (SEQ / 4);
    #pragma unroll
    for (int it = 0; it < 64; ++it)
        ob[it * 256 + t] = dreg + hreg[it];
}

extern "C" void kernel_launch(void* const* d_in, const int* in_sizes, int n_in,
                              void* d_out, int out_size, void* d_ws, size_t ws_size,
                              hipStream_t stream) {
    const float* head = (const float*)d_in[0];
    const float* dep  = (const float*)d_in[1];
    const float* W    = (const float*)d_in[2];
    const float* bias = (const float*)d_in[3];
    float* out = (float*)d_out;

    const size_t P = (size_t)BATCH * NL * SEQ;           // 262144 floats
    float* hbuf = (float*)d_ws;                          // 1 MiB
    float* dbuf = hbuf + P;                              // 1 MiB

    // Probes first (full-size d_out writes), then the real pipeline
    // overwrites everything -> output unchanged, deterministic.
    alab_probe0<<<2048, 256, 0, stream>>>(out);
    alab_probe1<<<2048, 256, 0, stream>>>(out);
    alab_proj7<<<BATCH * 64, 256, 0, stream>>>(head, dep, W, bias, hbuf, dbuf);
    alab_bcast8<<<BATCH * NL * 4, 256, 0, stream>>>(hbuf, dbuf, out);
}

// Round 19
// 108.870 us; speedup vs baseline: 2.6463x; 2.6463x over previous
//
#include <hip/hip_runtime.h>
#include <hip/hip_bf16.h>

#define BATCH 8
#define SEQ   512
#define DIM   512
#define NL    64

typedef float f32x4 __attribute__((ext_vector_type(4)));
using bf16x8 = __attribute__((ext_vector_type(8))) short;   // 8 bf16 = 4 VGPRs

// f32 -> bf16 RNE pair-pack via compiler-native casts.
static __device__ __forceinline__ unsigned short bf1c(float f) {
    __hip_bfloat16 h = (__hip_bfloat16)f;
    return *reinterpret_cast<unsigned short*>(&h);
}
static __device__ __forceinline__ unsigned bfpair(float a, float b) {
    return (unsigned)bf1c(a) | ((unsigned)bf1c(b) << 16);
}

// proj v7 (MFMA, self-contained) — byte-identical to rounds 14-18.
// h[b,l,i] = dot(head[b,i,:], W[l,0:512]) + bias[l]
// d[b,l,j] = dot(dep[b,j,:],  W[l,512:1024])
// Block = (b, itile16, hd); A staged as bf16 in LDS; B = f32 W rows
// converted in-register; 16 mfma_f32_16x16x32_bf16 per wave (2-acc ILP).
__global__ __launch_bounds__(256) void alab_proj7(
    const float* __restrict__ head, const float* __restrict__ dep,
    const float* __restrict__ W, const float* __restrict__ bias,
    float* __restrict__ hbuf, float* __restrict__ dbuf)
{
    __shared__ __align__(16) unsigned short A_lds[16 * 520];  // 16.25 KB
    const int bid   = blockIdx.x;
    const int hd    = bid & 1;                  // 0 = head->h, 1 = dep->d
    const int itile = (bid >> 1) & 31;
    const int b     = bid >> 6;
    const int i0    = itile * 16;

    const float* src = hd ? dep  : head;
    float*       dst = hd ? dbuf : hbuf;

    const float* arow = src + ((size_t)b * SEQ + i0) * DIM;
    #pragma unroll
    for (int u = threadIdx.x; u < 1024; u += 256) {
        const int row = u >> 6, kc = (u & 63) * 8;
        const float* p = arow + row * DIM + kc;
        const float4 f0 = *(const float4*)p;
        const float4 f1 = *(const float4*)(p + 4);
        uint4 wv = { bfpair(f0.x, f0.y), bfpair(f0.z, f0.w),
                     bfpair(f1.x, f1.y), bfpair(f1.z, f1.w) };
        *(uint4*)&A_lds[row * 520 + kc] = wv;
    }
    __syncthreads();

    const int lane = threadIdx.x & 63;
    const int w    = threadIdx.x >> 6;          // wave -> l quadrant
    const int lr   = lane & 15;                 // A: i-row / B: l-row / C: col
    const int kg   = lane >> 4;                 // k-group (8 bf16 each)

    const unsigned short* Ab = &A_lds[lr * 520 + kg * 8];
    const float* Wb = W + (size_t)(w * 16 + lr) * (2 * DIM) + hd * DIM + kg * 8;

    f32x4 acc0 = {0.f, 0.f, 0.f, 0.f}, acc1 = {0.f, 0.f, 0.f, 0.f};
    #pragma unroll
    for (int s = 0; s < 16; s += 2) {           // 2 accumulators for ILP
        const bf16x8 a0 = *(const bf16x8*)(Ab + (s + 0) * 32);
        const bf16x8 a1 = *(const bf16x8*)(Ab + (s + 1) * 32);
        const float4 w00 = *(const float4*)(Wb + (s + 0) * 32);
        const float4 w01 = *(const float4*)(Wb + (s + 0) * 32 + 4);
        const float4 w10 = *(const float4*)(Wb + (s + 1) * 32);
        const float4 w11 = *(const float4*)(Wb + (s + 1) * 32 + 4);
        union { bf16x8 v; unsigned u[4]; } b0, b1;
        b0.u[0] = bfpair(w00.x, w00.y); b0.u[1] = bfpair(w00.z, w00.w);
        b0.u[2] = bfpair(w01.x, w01.y); b0.u[3] = bfpair(w01.z, w01.w);
        b1.u[0] = bfpair(w10.x, w10.y); b1.u[1] = bfpair(w10.z, w10.w);
        b1.u[2] = bfpair(w11.x, w11.y); b1.u[3] = bfpair(w11.z, w11.w);
        acc0 = __builtin_amdgcn_mfma_f32_16x16x32_bf16(a0, b0.v, acc0, 0, 0, 0);
        acc1 = __builtin_amdgcn_mfma_f32_16x16x32_bf16(a1, b1.v, acc1, 0, 0, 0);
    }
    const f32x4 acc = acc0 + acc1;

    // C layout (m89-verified): col = lane&15 (=l), row = (lane>>4)*4 + reg (=i)
    const int l = w * 16 + lr;
    const int i = i0 + kg * 4;
    const float bb = hd ? 0.f : bias[l];        // bias folded into h
    const f32x4 r = acc + bb;
    *(f32x4*)(dst + ((size_t)b * NL + l) * SEQ + i) = r;
}

// bcast v8 — byte-identical to round 17. out[b,l,i,j] = h[b,l,i] + d[b,l,j].
// 2048 blocks x 256 KB contiguous span; store operands pure-register
// (dreg + static hreg[64]); zero LDS/barriers/loads in the store loop.
// Measured at 5.4 TB/s == the pure-store probe rate for incompressible
// data (R18 probes: zeros 6.9 TB/s, varying 5.4 TB/s — content-limited).
__global__ __launch_bounds__(256) void alab_bcast8(
    const float* __restrict__ hbuf, const float* __restrict__ dbuf,
    float* __restrict__ out)
{
    const int t  = threadIdx.x;
    const int q  = blockIdx.x & 3;              // quarter-tile (128 rows)
    const int bl = blockIdx.x >> 2;             // b*NL + l
    const int j4 = t & 127;                     // f32x4 column
    const int rh = t >> 7;                      // row parity
    const int r0 = q * 128;

    const f32x4 dreg = ((const f32x4*)dbuf)[(size_t)bl * (SEQ / 4) + j4];

    float hreg[64];
    const float* hb = hbuf + (size_t)bl * SEQ + r0 + rh;
    #pragma unroll
    for (int it = 0; it < 64; ++it) hreg[it] = hb[it * 2];

    f32x4* ob = (f32x4*)out + ((size_t)bl * SEQ + r0) * (SEQ / 4);
    #pragma unroll
    for (int it = 0; it < 64; ++it)
        ob[it * 256 + t] = dreg + hreg[it];
}

extern "C" void kernel_launch(void* const* d_in, const int* in_sizes, int n_in,
                              void* d_out, int out_size, void* d_ws, size_t ws_size,
                              hipStream_t stream) {
    const float* head = (const float*)d_in[0];
    const float* dep  = (const float*)d_in[1];
    const float* W    = (const float*)d_in[2];
    const float* bias = (const float*)d_in[3];
    float* out = (float*)d_out;

    const size_t P = (size_t)BATCH * NL * SEQ;           // 262144 floats
    float* hbuf = (float*)d_ws;                          // 1 MiB
    float* dbuf = hbuf + P;                              // 1 MiB

    alab_proj7<<<BATCH * 64, 256, 0, stream>>>(head, dep, W, bias, hbuf, dbuf);
    alab_bcast8<<<BATCH * NL * 4, 256, 0, stream>>>(hbuf, dbuf, out);
}